// Round 7
// baseline (2583.591 us; speedup 1.0000x reference)
//
#include <hip/hip_runtime.h>
#include <math.h>

#define NLAYER 4
#define DMODEL 256
#define ITEMS  32          // items per block (2 tokens each)
#define MROWS  64          // token rows per block
#define XS     264         // X LDS row stride (elems): 264*2B=528B
#define BS     776         // scratch LDS row stride (elems); 776*2=1552B, 16B-aligned
#define EPSV   1e-5f
#define NWAVES 16          // 1024 threads

typedef __attribute__((ext_vector_type(8))) short short8;
typedef __attribute__((ext_vector_type(4))) float f32x4;

// ws (bf16) layout offsets, in elements
#define OFF_WQKV 0
#define OFF_WO   786432
#define OFF_W1   1048576
#define OFF_W2   2097152
#define OFF_WL1  3145728
#define OFF_WL2  3211264
#define OFF_WR1  3244032
#define OFF_WR2  3309568
#define WS_ELEMS 3342336

static __device__ __forceinline__ float b2f(short s) {
  return __uint_as_float(((unsigned)(unsigned short)s) << 16);
}
static __device__ __forceinline__ short f2bf(float f) {   // RNE fp32->bf16
  unsigned u = __float_as_uint(f);
  return (short)((u + 0x7fffu + ((u >> 16) & 1u)) >> 16);
}
static __device__ __forceinline__ float gelu_f(float x) { // exact gelu (approximate=False)
  return 0.5f * x * (1.0f + erff(x * 0.70710678118654752f));
}

// C = A @ W^T + bias (optional gelu). K = 256 fixed.
// A: LDS bf16, row index = rmul*m + radd, row stride `as`.
// W: global bf16, N rows of 256 (row n == output column n).
// Out: LDS Bf, rows [oro, oro+16*MT), cols [oc0, oc0+N).
// Waves [WBASE, WBASE+WN) stripe the N-tile dim, PAIR tiles each per iter.
// Per-output-tile K-chain (kt ascending) identical to prior rounds -> bit-exact.
// B operands explicitly double-buffered in regs to hide L2 latency.
template<int MT, int PAIR, int WBASE, int WN>
static __device__ void gemm_lds(const short* A, int as, int rmul, int radd,
                                const short* __restrict__ W,
                                const float* __restrict__ bias,
                                short* Out, int oc0, int oro,
                                int N, int act, int tid)
{
  const int wave = tid >> 6;
  if (WN != NWAVES && (wave < WBASE || wave >= WBASE + WN)) return;
  const int lane = tid & 63;
  const int lm = lane & 15;
  const int q  = lane >> 4;
  const int ntiles = N >> 4;
  const f32x4 z = {0.f, 0.f, 0.f, 0.f};
  for (int nb = (wave - WBASE) * PAIR; nb < ntiles; nb += WN * PAIR) {
    f32x4 acc[MT][PAIR];
    #pragma unroll
    for (int mt = 0; mt < MT; ++mt)
      #pragma unroll
      for (int p = 0; p < PAIR; ++p) acc[mt][p] = z;
    short8 b[PAIR];
    #pragma unroll
    for (int p = 0; p < PAIR; ++p)
      b[p] = *(const short8*)(W + ((nb + p) * 16 + lm) * 256 + q * 8);
    #pragma unroll
    for (int kt = 0; kt < 256; kt += 32) {
      short8 bn[PAIR];
      if (kt < 224) {
        #pragma unroll
        for (int p = 0; p < PAIR; ++p)
          bn[p] = *(const short8*)(W + ((nb + p) * 16 + lm) * 256 + kt + 32 + q * 8);
      }
      #pragma unroll
      for (int mt = 0; mt < MT; ++mt) {
        short8 a = *(const short8*)(A + (rmul * (mt * 16 + lm) + radd) * as + kt + q * 8);
        #pragma unroll
        for (int p = 0; p < PAIR; ++p)
          acc[mt][p] = __builtin_amdgcn_mfma_f32_16x16x32_bf16(a, b[p], acc[mt][p], 0, 0, 0);
      }
      if (kt < 224) {
        #pragma unroll
        for (int p = 0; p < PAIR; ++p) b[p] = bn[p];
      }
    }
    #pragma unroll
    for (int mt = 0; mt < MT; ++mt) {
      #pragma unroll
      for (int p = 0; p < PAIR; ++p) {
        int col = (nb + p) * 16 + lm;
        float bv = bias[col];
        #pragma unroll
        for (int r = 0; r < 4; ++r) {
          float v = acc[mt][p][r] + bv;
          if (act) v = gelu_f(v);
          Out[(oro + mt * 16 + q * 4 + r) * BS + oc0 + col] = f2bf(v);
        }
      }
    }
  }
}

// FFN second GEMM: accumulate Bf[0..512) @ W2[:, wc0..wc0+512)^T into acc.
// Wave w owns output cols [16w, 16w+16). W row stride 1024 (ff).
// kt-ascending chain per output element identical to prior rounds -> bit-exact.
static __device__ void gemm_acc512(f32x4 acc[4], const short* A,
                                   const short* __restrict__ W, int wc0, int tid)
{
  const int wave = tid >> 6, lane = tid & 63;
  const int lm = lane & 15, q = lane >> 4;
  const short* wrow = W + (wave * 16 + lm) * 1024 + wc0 + q * 8;
  short8 b = *(const short8*)(wrow);
  #pragma unroll
  for (int kt = 0; kt < 512; kt += 32) {
    short8 bn;
    if (kt < 480) bn = *(const short8*)(wrow + kt + 32);
    #pragma unroll
    for (int mt = 0; mt < 4; ++mt) {
      short8 a = *(const short8*)(A + (mt * 16 + lm) * BS + kt + q * 8);
      acc[mt] = __builtin_amdgcn_mfma_f32_16x16x32_bf16(a, b, acc[mt], 0, 0, 0);
    }
    if (kt < 480) b = bn;
  }
}

// InstanceNorm over 256 cols per row: X = inorm(Bf_[0..256) [+ X]).
// 4 threads per row, shuffle-reduce within the quad. (R0-verbatim body.)
static __device__ void inorm_pass(short* Xs_, const short* Bf_, bool addx, int tid)
{
  if (tid >= MROWS * 4) return;
  int r = tid >> 2, sub = tid & 3;
  const short* bp = Bf_ + r * BS + sub * 64;
  short* xp = Xs_ + r * XS + sub * 64;
  float sum = 0.f, sq = 0.f;
  for (int e = 0; e < 64; ++e) {
    float v = b2f(bp[e]);
    if (addx) v += b2f(xp[e]);
    sum += v; sq += v * v;
  }
  sum += __shfl_xor(sum, 1); sq += __shfl_xor(sq, 1);
  sum += __shfl_xor(sum, 2); sq += __shfl_xor(sq, 2);
  float mean = sum * (1.f / 256.f);
  float rstd = rsqrtf(sq * (1.f / 256.f) - mean * mean + EPSV);
  for (int e = 0; e < 64; ++e) {
    float v = b2f(bp[e]);
    if (addx) v += b2f(xp[e]);
    xp[e] = f2bf((v - mean) * rstd);
  }
}

struct PrepArgs {
  const float* src[8];
  int n[8];
  int off[8];
};

__global__ void prep_weights(PrepArgs pa, short* __restrict__ dst, int total)
{
  int idx = blockIdx.x * 256 + threadIdx.x;
  if (idx >= total) return;
  int j = 0, off = idx;
  while (j < 7 && off >= pa.n[j]) { off -= pa.n[j]; ++j; }
  dst[pa.off[j] + off] = f2bf(pa.src[j][off]);
}

__global__ __launch_bounds__(1024, 4)
void fused_encoder(const float* __restrict__ children,
                   const float* __restrict__ roles,
                   const short* __restrict__ ws,
                   const float* __restrict__ g_bqkv,
                   const float* __restrict__ g_bo,
                   const float* __restrict__ g_b1,
                   const float* __restrict__ g_b2,
                   const float* __restrict__ g_bl1, const float* __restrict__ g_bl2,
                   const float* __restrict__ g_br1, const float* __restrict__ g_br2,
                   const float* __restrict__ g_lng, const float* __restrict__ g_lnb,
                   float* __restrict__ out)
{
  __shared__ __align__(16) short Xs[MROWS * XS];   // residual stream (bf16)   33792 B
  __shared__ __align__(16) short Bf[MROWS * BS];   // scratch: Q|K|V, O, hid   99328 B
  // total 133120 B -> 1 block/CU; 16 waves = 4/SIMD

  const int tid = threadIdx.x;
  const int bid = blockIdx.x;

  // ---- X = children + roles[tok] ---- (R0 body; stride scaled to 1024 threads)
  {
    const float* src = children + (long)bid * MROWS * DMODEL;
    for (int e = tid * 4; e < MROWS * DMODEL; e += 4096) {
      int row = e >> 8, col = e & 255;
      float4 v = *(const float4*)(src + e);
      const float* rl = roles + (row & 1) * DMODEL + col;
      short* xp = Xs + row * XS + col;
      xp[0] = f2bf(v.x + rl[0]);
      xp[1] = f2bf(v.y + rl[1]);
      xp[2] = f2bf(v.z + rl[2]);
      xp[3] = f2bf(v.w + rl[3]);
    }
  }
  __syncthreads();

  for (int l = 0; l < NLAYER; ++l) {
    const short* Wqkv = ws + OFF_WQKV + l * 768 * 256;
    const short* Wo   = ws + OFF_WO   + l * 256 * 256;
    const short* W1   = ws + OFF_W1   + l * 1024 * 256;
    const short* W2   = ws + OFF_W2   + l * 256 * 1024;

    // Q,K,V in ONE GEMM -> Bf cols [0,768): 48 tiles, 16 waves x 3
    gemm_lds<4, 3, 0, NWAVES>(Xs, XS, 1, 0, Wqkv, g_bqkv + l * 768, Bf, 0, 0, 768, 0, tid);
    __syncthreads();

    // fused scores + softmax + att.V: one thread per (item, head, tok).
    // Q cols [0,256), K [256,512), V [512,768). O overwrites the thread's own
    // (dead) Q segment -> race-free. Statements identical to prior rounds.
    if (tid < ITEMS * 8) {
      int i = tid >> 3, h = (tid >> 1) & 3, tk = tid & 1;
      const short* qp = Bf + (2 * i + tk) * BS + h * 64;
      const short* k0 = Bf + (2 * i    ) * BS + 256 + h * 64;
      const short* k1 = Bf + (2 * i + 1) * BS + 256 + h * 64;
      float s0 = 0.f, s1 = 0.f;
      for (int e = 0; e < 64; ++e) {
        float qv = b2f(qp[e]);
        s0 += qv * b2f(k0[e]);
        s1 += qv * b2f(k1[e]);
      }
      s0 *= 0.125f; s1 *= 0.125f;                 // 1/sqrt(dh=64)
      float mx = fmaxf(s0, s1);
      float e0 = __expf(s0 - mx), e1 = __expf(s1 - mx);
      float inv = 1.f / (e0 + e1);
      float a0 = e0 * inv, a1 = e1 * inv;
      const short* v0 = Bf + (2 * i    ) * BS + 512 + h * 64;
      const short* v1 = Bf + (2 * i + 1) * BS + 512 + h * 64;
      short* op = Bf + (2 * i + tk) * BS + h * 64;   // own Q segment (dead)
      for (int e = 0; e < 64; ++e)
        op[e] = f2bf(a0 * b2f(v0[e]) + a1 * b2f(v1[e]));
    }
    __syncthreads();

    // O @ Wo^T + bo: A = Bf cols [0,256), out -> Bf cols [256,512) (disjoint)
    gemm_lds<4, 1, 0, NWAVES>(Bf, BS, 1, 0, Wo, g_bo + l * 256, Bf, 256, 0, 256, 0, tid);
    __syncthreads();
    inorm_pass(Xs, Bf + 256, true, tid);   // X = inorm(X + oproj)
    __syncthreads();

    // FFN, ff split into 2 chunks of 512; out accumulators persist in regs
    f32x4 facc[4];
    {
      const f32x4 z = {0.f, 0.f, 0.f, 0.f};
      #pragma unroll
      for (int mt = 0; mt < 4; ++mt) facc[mt] = z;
    }
    for (int ch = 0; ch < 2; ++ch) {
      gemm_lds<4, 2, 0, NWAVES>(Xs, XS, 1, 0, W1 + ch * 512 * 256, g_b1 + l * 1024 + ch * 512,
                                Bf, 0, 0, 512, 1, tid);   // hidden = gelu(...)
      __syncthreads();
      gemm_acc512(facc, Bf, W2, ch * 512, tid);           // out += hidden @ W2chunk^T
      __syncthreads();
    }
    // y = facc + b2 + X -> Bf cols [0,256); wave owns 16 cols
    {
      const int wave = tid >> 6, lane = tid & 63, lm = lane & 15, q = lane >> 4;
      int col = wave * 16 + lm;
      float bv = g_b2[l * 256 + col];
      #pragma unroll
      for (int mt = 0; mt < 4; ++mt) {
        #pragma unroll
        for (int r = 0; r < 4; ++r) {
          int row = mt * 16 + q * 4 + r;
          Bf[row * BS + col] = f2bf(facc[mt][r] + bv + b2f(Xs[row * XS + col]));
        }
      }
    }
    __syncthreads();
    inorm_pass(Xs, Bf, false, tid);  // X = inorm(y)
    __syncthreads();
  }

  // ---- heads: left MLP on waves 0..7, right MLP on waves 8..15 (parallel) ----
  gemm_lds<2, 2, 0, 8>(Xs, XS, 2, 0, ws + OFF_WL1, g_bl1, Bf, 0, 0, 256, 1, tid);     // rows 0..31, cols [0,256)
  gemm_lds<2, 2, 8, 8>(Xs, XS, 2, 1, ws + OFF_WR1, g_br1, Bf, 256, 0, 256, 1, tid);   // rows 0..31, cols [256,512)
  __syncthreads();
  gemm_lds<2, 1, 0, 8>(Bf, BS, 1, 0, ws + OFF_WL2, g_bl2, Bf, 0, 32, 128, 0, tid);    // rows 32..63, cols [0,128)
  gemm_lds<2, 1, 8, 8>(Bf + 256, BS, 1, 0, ws + OFF_WR2, g_br2, Bf, 128, 32, 128, 0, tid); // rows 32..63, cols [128,256)
  __syncthreads();

  // mat_scores = dot(left2, right2)/sqrt(128): 8 threads per item (R0-verbatim)
  if (tid < ITEMS * 8) {
    int i = tid >> 3, sub = tid & 7;
    const short* lp = Bf + (32 + i) * BS + sub * 16;
    float acc = 0.f;
    for (int j = 0; j < 16; ++j) acc += b2f(lp[j]) * b2f(lp[128 + j]);
    acc += __shfl_xor(acc, 1);
    acc += __shfl_xor(acc, 2);
    acc += __shfl_xor(acc, 4);
    if (sub == 0) out[bid * ITEMS + i] = acc * 0.088388347648318447f;
  }
  // src = LayerNorm(x0 + x1) * g + b  (R0-verbatim)
  if (tid < ITEMS * 8) {
    int i = tid >> 3, sub = tid & 7;
    const short* x0 = Xs + (2 * i) * XS + sub * 32;
    const short* x1 = Xs + (2 * i + 1) * XS + sub * 32;
    float sum = 0.f, sq = 0.f;
    for (int e = 0; e < 32; ++e) {
      float v = b2f(x0[e]) + b2f(x1[e]);
      sum += v; sq += v * v;
    }
    sum += __shfl_xor(sum, 1); sq += __shfl_xor(sq, 1);
    sum += __shfl_xor(sum, 2); sq += __shfl_xor(sq, 2);
    sum += __shfl_xor(sum, 4); sq += __shfl_xor(sq, 4);
    float mean = sum * (1.f / 256.f);
    float rstd = rsqrtf(sq * (1.f / 256.f) - mean * mean + EPSV);
    float* op = out + 65536 + ((long)bid * ITEMS + i) * DMODEL + sub * 32;
    for (int e = 0; e < 32; ++e) {
      int c = sub * 32 + e;
      float v = b2f(x0[e]) + b2f(x1[e]);
      op[e] = (v - mean) * rstd * g_lng[c] + g_lnb[c];
    }
  }
}

extern "C" void kernel_launch(void* const* d_in, const int* in_sizes, int n_in,
                              void* d_out, int out_size, void* d_ws, size_t ws_size,
                              hipStream_t stream)
{
  (void)in_sizes; (void)n_in; (void)out_size; (void)ws_size;
  const float* children = (const float*)d_in[0];
  const float* roles    = (const float*)d_in[1];
  const float* Wqkv     = (const float*)d_in[2];
  const float* bqkv     = (const float*)d_in[3];
  const float* Wo       = (const float*)d_in[4];
  const float* bo       = (const float*)d_in[5];
  const float* W1       = (const float*)d_in[6];
  const float* b1       = (const float*)d_in[7];
  const float* W2       = (const float*)d_in[8];
  const float* b2       = (const float*)d_in[9];
  const float* Wl1      = (const float*)d_in[10];
  const float* bl1      = (const float*)d_in[11];
  const float* Wl2      = (const float*)d_in[12];
  const float* bl2      = (const float*)d_in[13];
  const float* Wr1      = (const float*)d_in[14];
  const float* br1      = (const float*)d_in[15];
  const float* Wr2      = (const float*)d_in[16];
  const float* br2      = (const float*)d_in[17];
  const float* ln_g     = (const float*)d_in[18];
  const float* ln_b     = (const float*)d_in[19];

  short* ws = (short*)d_ws;

  PrepArgs pa;
  pa.src[0] = Wqkv; pa.n[0] = 786432;  pa.off[0] = OFF_WQKV;
  pa.src[1] = Wo;   pa.n[1] = 262144;  pa.off[1] = OFF_WO;
  pa.src[2] = W1;   pa.n[2] = 1048576; pa.off[2] = OFF_W1;
  pa.src[3] = W2;   pa.n[3] = 1048576; pa.off[3] = OFF_W2;
  pa.src[4] = Wl1;  pa.n[4] = 65536;   pa.off[4] = OFF_WL1;
  pa.src[5] = Wl2;  pa.n[5] = 32768;   pa.off[5] = OFF_WL2;
  pa.src[6] = Wr1;  pa.n[6] = 65536;   pa.off[6] = OFF_WR1;
  pa.src[7] = Wr2;  pa.n[7] = 32768;   pa.off[7] = OFF_WR2;

  prep_weights<<<(WS_ELEMS + 255) / 256, 256, 0, stream>>>(pa, ws, WS_ELEMS);
  fused_encoder<<<2048, 1024, 0, stream>>>(children, roles, ws,
      bqkv, bo, b1, b2, bl1, bl2, br1, br2, ln_g, ln_b, (float*)d_out);
}

// Round 8
// 2399.726 us; speedup vs baseline: 1.0766x; 1.0766x over previous
//
#include <hip/hip_runtime.h>
#include <math.h>

#define NLAYER 4
#define DMODEL 256
#define ITEMS  32          // items per block (2 tokens each)
#define MROWS  64          // token rows per block
#define XS     264         // X LDS row stride (elems): 264*2B=528B
#define BS     776         // scratch LDS row stride (elems); 776*2=1552B, 16B-aligned
#define EPSV   1e-5f
#define NWAVES 16          // 1024 threads

typedef __attribute__((ext_vector_type(8))) short short8;
typedef __attribute__((ext_vector_type(4))) float f32x4;

// ws (bf16) layout offsets, in elements
#define OFF_WQKV 0
#define OFF_WO   786432
#define OFF_W1   1048576
#define OFF_W2   2097152
#define OFF_WL1  3145728
#define OFF_WL2  3211264
#define OFF_WR1  3244032
#define OFF_WR2  3309568
#define WS_ELEMS 3342336

static __device__ __forceinline__ float b2f(short s) {
  return __uint_as_float(((unsigned)(unsigned short)s) << 16);
}
static __device__ __forceinline__ short f2bf(float f) {   // RNE fp32->bf16
  unsigned u = __float_as_uint(f);
  return (short)((u + 0x7fffu + ((u >> 16) & 1u)) >> 16);
}
static __device__ __forceinline__ float gelu_f(float x) { // exact gelu (approximate=False)
  return 0.5f * x * (1.0f + erff(x * 0.70710678118654752f));
}

// C = A @ W^T + bias (optional gelu). K = 256 fixed.
// A: LDS bf16, row index = rmul*m + radd, row stride `as`.
// W: global bf16, N rows of 256 (row n == output column n).
// Out: LDS Bf, rows [oro, oro+16*MT), cols [oc0, oc0+N).
// Waves [WBASE, WBASE+WN) stripe the N-tile dim, PAIR tiles each per iter.
// Inner loop is the R6-verbatim shape (simple, no prefetch — avoids spills).
// Per-output-tile K-chain (kt ascending) identical to prior rounds -> bit-exact.
template<int MT, int PAIR, int WBASE, int WN>
static __device__ void gemm_lds(const short* A, int as, int rmul, int radd,
                                const short* __restrict__ W,
                                const float* __restrict__ bias,
                                short* Out, int oc0, int oro,
                                int N, int act, int tid)
{
  const int wave = tid >> 6;
  if (WN != NWAVES && (wave < WBASE || wave >= WBASE + WN)) return;
  const int lane = tid & 63;
  const int lm = lane & 15;
  const int q  = lane >> 4;
  const int ntiles = N >> 4;
  const f32x4 z = {0.f, 0.f, 0.f, 0.f};
  for (int nb = (wave - WBASE) * PAIR; nb < ntiles; nb += WN * PAIR) {
    f32x4 acc[MT][PAIR];
    #pragma unroll
    for (int mt = 0; mt < MT; ++mt)
      #pragma unroll
      for (int p = 0; p < PAIR; ++p) acc[mt][p] = z;
    #pragma unroll 4
    for (int kt = 0; kt < 256; kt += 32) {
      short8 b[PAIR];
      #pragma unroll
      for (int p = 0; p < PAIR; ++p)
        b[p] = *(const short8*)(W + ((nb + p) * 16 + lm) * 256 + kt + q * 8);
      #pragma unroll
      for (int mt = 0; mt < MT; ++mt) {
        short8 a = *(const short8*)(A + (rmul * (mt * 16 + lm) + radd) * as + kt + q * 8);
        #pragma unroll
        for (int p = 0; p < PAIR; ++p)
          acc[mt][p] = __builtin_amdgcn_mfma_f32_16x16x32_bf16(a, b[p], acc[mt][p], 0, 0, 0);
      }
    }
    #pragma unroll
    for (int mt = 0; mt < MT; ++mt) {
      #pragma unroll
      for (int p = 0; p < PAIR; ++p) {
        int col = (nb + p) * 16 + lm;
        float bv = bias[col];
        #pragma unroll
        for (int r = 0; r < 4; ++r) {
          float v = acc[mt][p][r] + bv;
          if (act) v = gelu_f(v);
          Out[(oro + mt * 16 + q * 4 + r) * BS + oc0 + col] = f2bf(v);
        }
      }
    }
  }
}

// FFN second GEMM: accumulate Bf[0..512) @ W2[:, wc0..wc0+512)^T into acc.
// Wave w owns output cols [16w, 16w+16). W row stride 1024 (ff). (R6-verbatim.)
static __device__ void gemm_acc512(f32x4 acc[4], const short* A,
                                   const short* __restrict__ W, int wc0, int tid)
{
  const int wave = tid >> 6, lane = tid & 63;
  const int lm = lane & 15, q = lane >> 4;
  #pragma unroll 2
  for (int kt = 0; kt < 512; kt += 32) {
    short8 b = *(const short8*)(W + (wave * 16 + lm) * 1024 + wc0 + kt + q * 8);
    #pragma unroll
    for (int mt = 0; mt < 4; ++mt) {
      short8 a = *(const short8*)(A + (mt * 16 + lm) * BS + kt + q * 8);
      acc[mt] = __builtin_amdgcn_mfma_f32_16x16x32_bf16(a, b, acc[mt], 0, 0, 0);
    }
  }
}

// InstanceNorm over 256 cols per row: X = inorm(Bf_[0..256) [+ X]).
// 4 threads per row, shuffle-reduce within the quad. (R0-verbatim body.)
static __device__ void inorm_pass(short* Xs_, const short* Bf_, bool addx, int tid)
{
  if (tid >= MROWS * 4) return;
  int r = tid >> 2, sub = tid & 3;
  const short* bp = Bf_ + r * BS + sub * 64;
  short* xp = Xs_ + r * XS + sub * 64;
  float sum = 0.f, sq = 0.f;
  for (int e = 0; e < 64; ++e) {
    float v = b2f(bp[e]);
    if (addx) v += b2f(xp[e]);
    sum += v; sq += v * v;
  }
  sum += __shfl_xor(sum, 1); sq += __shfl_xor(sq, 1);
  sum += __shfl_xor(sum, 2); sq += __shfl_xor(sq, 2);
  float mean = sum * (1.f / 256.f);
  float rstd = rsqrtf(sq * (1.f / 256.f) - mean * mean + EPSV);
  for (int e = 0; e < 64; ++e) {
    float v = b2f(bp[e]);
    if (addx) v += b2f(xp[e]);
    xp[e] = f2bf((v - mean) * rstd);
  }
}

struct PrepArgs {
  const float* src[8];
  int n[8];
  int off[8];
};

__global__ void prep_weights(PrepArgs pa, short* __restrict__ dst, int total)
{
  int idx = blockIdx.x * 256 + threadIdx.x;
  if (idx >= total) return;
  int j = 0, off = idx;
  while (j < 7 && off >= pa.n[j]) { off -= pa.n[j]; ++j; }
  dst[pa.off[j] + off] = f2bf(pa.src[j][off]);
}

__global__ __launch_bounds__(1024)
void fused_encoder(const float* __restrict__ children,
                   const float* __restrict__ roles,
                   const short* __restrict__ ws,
                   const float* __restrict__ g_bqkv,
                   const float* __restrict__ g_bo,
                   const float* __restrict__ g_b1,
                   const float* __restrict__ g_b2,
                   const float* __restrict__ g_bl1, const float* __restrict__ g_bl2,
                   const float* __restrict__ g_br1, const float* __restrict__ g_br2,
                   const float* __restrict__ g_lng, const float* __restrict__ g_lnb,
                   float* __restrict__ out)
{
  __shared__ __align__(16) short Xs[MROWS * XS];   // residual stream (bf16)   33792 B
  __shared__ __align__(16) short Bf[MROWS * BS];   // scratch: Q|K|V, O, hid   99328 B
  // total 133120 B -> 1 block/CU; 16 waves = 4/SIMD

  const int tid = threadIdx.x;
  const int bid = blockIdx.x;

  // ---- X = children + roles[tok] ---- (R0 body; stride scaled to 1024 threads)
  {
    const float* src = children + (long)bid * MROWS * DMODEL;
    for (int e = tid * 4; e < MROWS * DMODEL; e += 4096) {
      int row = e >> 8, col = e & 255;
      float4 v = *(const float4*)(src + e);
      const float* rl = roles + (row & 1) * DMODEL + col;
      short* xp = Xs + row * XS + col;
      xp[0] = f2bf(v.x + rl[0]);
      xp[1] = f2bf(v.y + rl[1]);
      xp[2] = f2bf(v.z + rl[2]);
      xp[3] = f2bf(v.w + rl[3]);
    }
  }
  __syncthreads();

  for (int l = 0; l < NLAYER; ++l) {
    const short* Wqkv = ws + OFF_WQKV + l * 768 * 256;
    const short* Wo   = ws + OFF_WO   + l * 256 * 256;
    const short* W1   = ws + OFF_W1   + l * 1024 * 256;
    const short* W2   = ws + OFF_W2   + l * 256 * 1024;

    // Q,K,V in ONE GEMM -> Bf cols [0,768): 48 tiles, 16 waves x 1, 3 iters
    gemm_lds<4, 1, 0, NWAVES>(Xs, XS, 1, 0, Wqkv, g_bqkv + l * 768, Bf, 0, 0, 768, 0, tid);
    __syncthreads();

    // fused scores + softmax + att.V: one thread per (item, head, tok).
    // Q cols [0,256), K [256,512), V [512,768). O overwrites the thread's own
    // (dead) Q segment -> race-free. Statements identical to prior rounds.
    if (tid < ITEMS * 8) {
      int i = tid >> 3, h = (tid >> 1) & 3, tk = tid & 1;
      const short* qp = Bf + (2 * i + tk) * BS + h * 64;
      const short* k0 = Bf + (2 * i    ) * BS + 256 + h * 64;
      const short* k1 = Bf + (2 * i + 1) * BS + 256 + h * 64;
      float s0 = 0.f, s1 = 0.f;
      for (int e = 0; e < 64; ++e) {
        float qv = b2f(qp[e]);
        s0 += qv * b2f(k0[e]);
        s1 += qv * b2f(k1[e]);
      }
      s0 *= 0.125f; s1 *= 0.125f;                 // 1/sqrt(dh=64)
      float mx = fmaxf(s0, s1);
      float e0 = __expf(s0 - mx), e1 = __expf(s1 - mx);
      float inv = 1.f / (e0 + e1);
      float a0 = e0 * inv, a1 = e1 * inv;
      const short* v0 = Bf + (2 * i    ) * BS + 512 + h * 64;
      const short* v1 = Bf + (2 * i + 1) * BS + 512 + h * 64;
      short* op = Bf + (2 * i + tk) * BS + h * 64;   // own Q segment (dead)
      for (int e = 0; e < 64; ++e)
        op[e] = f2bf(a0 * b2f(v0[e]) + a1 * b2f(v1[e]));
    }
    __syncthreads();

    // O @ Wo^T + bo: A = Bf cols [0,256), out -> Bf cols [256,512) (disjoint)
    gemm_lds<4, 1, 0, NWAVES>(Bf, BS, 1, 0, Wo, g_bo + l * 256, Bf, 256, 0, 256, 0, tid);
    __syncthreads();
    inorm_pass(Xs, Bf + 256, true, tid);   // X = inorm(X + oproj)
    __syncthreads();

    // FFN, ff split into 2 chunks of 512; out accumulators persist in regs
    f32x4 facc[4];
    {
      const f32x4 z = {0.f, 0.f, 0.f, 0.f};
      #pragma unroll
      for (int mt = 0; mt < 4; ++mt) facc[mt] = z;
    }
    for (int ch = 0; ch < 2; ++ch) {
      gemm_lds<4, 2, 0, NWAVES>(Xs, XS, 1, 0, W1 + ch * 512 * 256, g_b1 + l * 1024 + ch * 512,
                                Bf, 0, 0, 512, 1, tid);   // hidden = gelu(...)
      __syncthreads();
      gemm_acc512(facc, Bf, W2, ch * 512, tid);           // out += hidden @ W2chunk^T
      __syncthreads();
    }
    // y = facc + b2 + X -> Bf cols [0,256); wave owns 16 cols
    {
      const int wave = tid >> 6, lane = tid & 63, lm = lane & 15, q = lane >> 4;
      int col = wave * 16 + lm;
      float bv = g_b2[l * 256 + col];
      #pragma unroll
      for (int mt = 0; mt < 4; ++mt) {
        #pragma unroll
        for (int r = 0; r < 4; ++r) {
          int row = mt * 16 + q * 4 + r;
          Bf[row * BS + col] = f2bf(facc[mt][r] + bv + b2f(Xs[row * XS + col]));
        }
      }
    }
    __syncthreads();
    inorm_pass(Xs, Bf, false, tid);  // X = inorm(y)
    __syncthreads();
  }

  // ---- heads: left MLP on waves 0..7, right MLP on waves 8..15 (parallel) ----
  gemm_lds<2, 2, 0, 8>(Xs, XS, 2, 0, ws + OFF_WL1, g_bl1, Bf, 0, 0, 256, 1, tid);     // rows 0..31, cols [0,256)
  gemm_lds<2, 2, 8, 8>(Xs, XS, 2, 1, ws + OFF_WR1, g_br1, Bf, 256, 0, 256, 1, tid);   // rows 0..31, cols [256,512)
  __syncthreads();
  gemm_lds<2, 1, 0, 8>(Bf, BS, 1, 0, ws + OFF_WL2, g_bl2, Bf, 0, 32, 128, 0, tid);    // rows 32..63, cols [0,128)
  gemm_lds<2, 1, 8, 8>(Bf + 256, BS, 1, 0, ws + OFF_WR2, g_br2, Bf, 128, 32, 128, 0, tid); // rows 32..63, cols [128,256)
  __syncthreads();

  // mat_scores = dot(left2, right2)/sqrt(128): 8 threads per item (R0-verbatim)
  if (tid < ITEMS * 8) {
    int i = tid >> 3, sub = tid & 7;
    const short* lp = Bf + (32 + i) * BS + sub * 16;
    float acc = 0.f;
    for (int j = 0; j < 16; ++j) acc += b2f(lp[j]) * b2f(lp[128 + j]);
    acc += __shfl_xor(acc, 1);
    acc += __shfl_xor(acc, 2);
    acc += __shfl_xor(acc, 4);
    if (sub == 0) out[bid * ITEMS + i] = acc * 0.088388347648318447f;
  }
  // src = LayerNorm(x0 + x1) * g + b  (R0-verbatim)
  if (tid < ITEMS * 8) {
    int i = tid >> 3, sub = tid & 7;
    const short* x0 = Xs + (2 * i) * XS + sub * 32;
    const short* x1 = Xs + (2 * i + 1) * XS + sub * 32;
    float sum = 0.f, sq = 0.f;
    for (int e = 0; e < 32; ++e) {
      float v = b2f(x0[e]) + b2f(x1[e]);
      sum += v; sq += v * v;
    }
    sum += __shfl_xor(sum, 1); sq += __shfl_xor(sq, 1);
    sum += __shfl_xor(sum, 2); sq += __shfl_xor(sq, 2);
    sum += __shfl_xor(sum, 4); sq += __shfl_xor(sq, 4);
    float mean = sum * (1.f / 256.f);
    float rstd = rsqrtf(sq * (1.f / 256.f) - mean * mean + EPSV);
    float* op = out + 65536 + ((long)bid * ITEMS + i) * DMODEL + sub * 32;
    for (int e = 0; e < 32; ++e) {
      int c = sub * 32 + e;
      float v = b2f(x0[e]) + b2f(x1[e]);
      op[e] = (v - mean) * rstd * g_lng[c] + g_lnb[c];
    }
  }
}

extern "C" void kernel_launch(void* const* d_in, const int* in_sizes, int n_in,
                              void* d_out, int out_size, void* d_ws, size_t ws_size,
                              hipStream_t stream)
{
  (void)in_sizes; (void)n_in; (void)out_size; (void)ws_size;
  const float* children = (const float*)d_in[0];
  const float* roles    = (const float*)d_in[1];
  const float* Wqkv     = (const float*)d_in[2];
  const float* bqkv     = (const float*)d_in[3];
  const float* Wo       = (const float*)d_in[4];
  const float* bo       = (const float*)d_in[5];
  const float* W1       = (const float*)d_in[6];
  const float* b1       = (const float*)d_in[7];
  const float* W2       = (const float*)d_in[8];
  const float* b2       = (const float*)d_in[9];
  const float* Wl1      = (const float*)d_in[10];
  const float* bl1      = (const float*)d_in[11];
  const float* Wl2      = (const float*)d_in[12];
  const float* bl2      = (const float*)d_in[13];
  const float* Wr1      = (const float*)d_in[14];
  const float* br1      = (const float*)d_in[15];
  const float* Wr2      = (const float*)d_in[16];
  const float* br2      = (const float*)d_in[17];
  const float* ln_g     = (const float*)d_in[18];
  const float* ln_b     = (const float*)d_in[19];

  short* ws = (short*)d_ws;

  PrepArgs pa;
  pa.src[0] = Wqkv; pa.n[0] = 786432;  pa.off[0] = OFF_WQKV;
  pa.src[1] = Wo;   pa.n[1] = 262144;  pa.off[1] = OFF_WO;
  pa.src[2] = W1;   pa.n[2] = 1048576; pa.off[2] = OFF_W1;
  pa.src[3] = W2;   pa.n[3] = 1048576; pa.off[3] = OFF_W2;
  pa.src[4] = Wl1;  pa.n[4] = 65536;   pa.off[4] = OFF_WL1;
  pa.src[5] = Wl2;  pa.n[5] = 32768;   pa.off[5] = OFF_WL2;
  pa.src[6] = Wr1;  pa.n[6] = 65536;   pa.off[6] = OFF_WR1;
  pa.src[7] = Wr2;  pa.n[7] = 32768;   pa.off[7] = OFF_WR2;

  prep_weights<<<(WS_ELEMS + 255) / 256, 256, 0, stream>>>(pa, ws, WS_ELEMS);
  fused_encoder<<<2048, 1024, 0, stream>>>(children, roles, ws,
      bqkv, bo, b1, b2, bl1, bl2, br1, br2, ln_g, ln_b, (float*)d_out);
}